// Round 3
// baseline (507.470 us; speedup 1.0000x reference)
//
#include <hip/hip_runtime.h>
#include <hip/hip_bf16.h>

typedef __attribute__((ext_vector_type(8))) short short8;
typedef __attribute__((ext_vector_type(4))) float floatx4;

__device__ __forceinline__ ushort f2bf(float x) {
    __hip_bfloat16 h = __float2bfloat16(x);
    return __builtin_bit_cast(ushort, h);
}
__device__ __forceinline__ float bf2f(ushort u) {
    __hip_bfloat16 h = __builtin_bit_cast(__hip_bfloat16, u);
    return __bfloat162float(h);
}

// fast tanh: 1 - 2/(e^{2z}+1); v_exp + v_rcp, ~1e-6 abs err
__device__ __forceinline__ float fast_tanh(float z) {
    float e = __expf(2.0f * z);
    return 1.0f - 2.0f * __builtin_amdgcn_rcpf(e + 1.0f);
}

// async global -> LDS, 16 bytes per lane. LDS dest is wave-uniform base + lane*16;
// per-lane GLOBAL source is arbitrary (exploited for the XOR bank swizzle).
__device__ __forceinline__ void gload_lds16(const ushort* g, ushort* l) {
    __builtin_amdgcn_global_load_lds(
        (const __attribute__((address_space(1))) unsigned int*)(const void*)g,
        (__attribute__((address_space(3))) unsigned int*)(void*)l,
        16, 0, 0);
}

// ---------------------------------------------------------------------------
// Fused prep (one dispatch): h0 pack + all three weight transposes.
// ---------------------------------------------------------------------------
__global__ void prep(const float* __restrict__ inp, const float* __restrict__ hz,
                     const float* __restrict__ Wf, const float* __restrict__ W1,
                     const float* __restrict__ W2,
                     ushort* __restrict__ h0, ushort* __restrict__ WfT,
                     ushort* __restrict__ W1T, ushort* __restrict__ W2T) {
    int bid = blockIdx.x;
    int tid = threadIdx.x;
    __shared__ float tile[32][33];
    if (bid < 32768) {
        const float* src = (bid < 16384) ? inp : hz;
        int half = (bid < 16384) ? 0 : 1;
        int b = bid - half * 16384;
        size_t i = ((size_t)b * 256 + tid) * 4;   // over 32768*512 floats
        size_t row = i >> 9;
        int col = (int)(i & 511);
        float4 v = *(const float4*)(src + i);
        ushort4 o = make_ushort4(f2bf(v.x), f2bf(v.y), f2bf(v.z), f2bf(v.w));
        *(ushort4*)(h0 + row * 1024 + half * 512 + col) = o;
    } else {
        int t = bid - 32768;
        const float* W;
        ushort* WT;
        int K = 1024, N = 1024;
        if (t < 1024)      { W = Wf; WT = WfT; }
        else if (t < 2048) { W = W1; WT = W1T; t -= 1024; }
        else               { W = W2; WT = W2T; t -= 2048; N = 512; }
        int tx = tid & 31, ty = tid >> 5;
        int nb = (t % (N / 32)) * 32, kb = (t / (N / 32)) * 32;
        #pragma unroll
        for (int j = ty; j < 32; j += 8)
            tile[j][tx] = W[(size_t)(kb + j) * N + nb + tx];
        __syncthreads();
        #pragma unroll
        for (int j = ty; j < 32; j += 8)
            WT[(size_t)(nb + j) * K + kb + tx] = f2bf(tile[tx][j]);
    }
}

// ---------------------------------------------------------------------------
// 128(M)x256(N)-tile bf16 MFMA GEMM, 512 threads / 8 waves.
// STRUCTURE (T3+T4+T5): ring-4 of 32-k panels in LDS (96 KB, 1 block/CU),
// counted s_waitcnt vmcnt(6) so 2-3 panels stay in flight ACROSS raw
// s_barriers (no vmcnt(0) drain in the main loop), setprio(1) around the
// 16-MFMA cluster. XOR bank swizzle (T2) and XCD-aware mapping (T1) retained.
//
// Safety invariants (raw-barrier schedule):
//  - availability: wave's own vmcnt(6) at iter t guarantees its contribution
//    to panel t+1 landed; barrier1(t)/barrier2(t) broadcast that to all waves
//    before any ds_read(t+1).
//  - slot reuse: STAGE(t+3) targets slot (t-1)&3; every wave's ds_read(t-1)
//    completed before its lgkmcnt(0)+barrier2(t-1), and STAGE(t+3) is only
//    issued after barrier2(t-1).
//
// MODE 1: out_bf = bf2f(A[row][col]) + 0.1*tanh(acc + bias)   (euler step)
// MODE 2: out_bf = relu(acc + bias)
// MODE 3: out_f32 = tanh(acc + bias)
// Grid 1-D: xcd=id&7 owns M-tiles [xcd*32, xcd*32+32); N-tiles innermost.
// ---------------------------------------------------------------------------
template <int MODE, int NOUT, int NX>
__global__ __launch_bounds__(512, 2) void gemm_ep(
    const ushort* __restrict__ A, const ushort* __restrict__ BT,
    const float* __restrict__ bias,
    ushort* __restrict__ outB, float* __restrict__ outF) {
    constexpr int K = 1024;
    constexpr int NT = 32;                 // 32-k panels
    __shared__ ushort As[4][128 * 32];     // 32 KB ring (4 slots)
    __shared__ ushort Bs[4][256 * 32];     // 64 KB ring (4 slots)

    const int tid = threadIdx.x;
    const int wave = tid >> 6, lane = tid & 63;

    const int id = blockIdx.x;
    const int inner = id >> 3;
    const int nTile = inner % NX;
    const int mTile = (id & 7) * 32 + inner / NX;
    const int mBase = mTile * 128;
    const int nBase = nTile * 256;
    const int waveM = wave >> 2;      // 0..1  (64-row band)
    const int waveN = wave & 3;       // 0..3  (64-col band)

    // Per-panel staging with XOR bank swizzle: physical 16B slot c holds
    // logical (row r=c>>2, quad q=(c&3)^((r>>1)&3)). Panel t is a flat +t*32
    // k-offset on the same global base; slot s&3 is a constant LDS offset.
    const int ca = wave * 64 + lane;
    const int ra = ca >> 2;
    const int qa = (ca & 3) ^ ((ra >> 1) & 3);
    const ushort* agA = A + (size_t)(mBase + ra) * K + qa * 8;
    const ushort* bg0 = BT + (size_t)(nBase + ra) * K + qa * 8;
    const ushort* bg1 = BT + (size_t)(nBase + ra + 128) * K + qa * 8;
    ushort* asD  = &As[0][0] + (size_t)(wave * 64) * 8;
    ushort* bsD0 = &Bs[0][0] + (size_t)(wave * 64) * 8;
    ushort* bsD1 = &Bs[0][0] + (size_t)(wave * 64 + 512) * 8;

    floatx4 acc[4][4];
    #pragma unroll
    for (int i = 0; i < 4; i++)
        #pragma unroll
        for (int j = 0; j < 4; j++) acc[i][j] = (floatx4)(0.f);

    const int mrow = lane & 15;
    const int g = lane >> 4;                  // logical k-quad
    const int pq = g ^ ((mrow >> 1) & 3);     // physical quad
    const int kqOff = pq * 8;

    // ds_read base pointers (per-thread row/quad component; slot+frag offsets
    // fold into ds_read immediates: A <= 28KB, B <= 53KB, both < 64KB)
    const ushort* aB = &As[0][0] + (waveM * 64 + mrow) * 32 + kqOff;
    const ushort* bB = &Bs[0][0] + (waveN * 64 + mrow) * 32 + kqOff;

    #define STAGE(t) do {                                          \
        const int s_ = (t) & 3;                                    \
        gload_lds16(agA + (t) * 32, asD  + s_ * 4096);             \
        gload_lds16(bg0 + (t) * 32, bsD0 + s_ * 8192);             \
        gload_lds16(bg1 + (t) * 32, bsD1 + s_ * 8192);             \
    } while (0)

    // prologue: stage panels 0..2 (9 loads); wait until panel 0 landed
    STAGE(0); STAGE(1); STAGE(2);
    asm volatile("s_waitcnt vmcnt(6)" ::: "memory");
    __builtin_amdgcn_s_barrier();

    #pragma unroll
    for (int t = 0; t < NT; ++t) {
        const int s = t & 3;
        short8 af[4], bfr[4];
        #pragma unroll
        for (int i = 0; i < 4; i++) {
            af[i]  = *(const short8*)(aB + s * 4096 + i * 512);
            bfr[i] = *(const short8*)(bB + s * 8192 + i * 512);
        }
        if (t + 3 < NT) {
            STAGE(t + 3);                                   // -> slot (t-1)&3
            asm volatile("s_waitcnt vmcnt(6)" ::: "memory"); // t+1 landed; t+2,t+3 in flight
        } else {
            asm volatile("s_waitcnt vmcnt(0)" ::: "memory"); // tail drain (last 3 iters)
        }
        __builtin_amdgcn_s_barrier();                        // barrier1: availability broadcast
        asm volatile("s_waitcnt lgkmcnt(0)" ::: "memory");
        __builtin_amdgcn_sched_barrier(0);                   // rule #18: pin MFMA after the wait
        __builtin_amdgcn_s_setprio(1);
        #pragma unroll
        for (int mt = 0; mt < 4; mt++)
            #pragma unroll
            for (int nt = 0; nt < 4; nt++)
                acc[mt][nt] = __builtin_amdgcn_mfma_f32_16x16x32_bf16(
                    af[mt], bfr[nt], acc[mt][nt], 0, 0, 0);
        __builtin_amdgcn_s_setprio(0);
        __builtin_amdgcn_sched_barrier(0);
        __builtin_amdgcn_s_barrier();                        // barrier2: protects slot reuse
    }
    #undef STAGE

    // epilogue: C/D layout col=lane&15, row=(lane>>4)*4+reg  [m89/m91]
    const int col0 = nBase + waveN * 64 + (lane & 15);
    const int row0 = mBase + waveM * 64 + (lane >> 4) * 4;
    #pragma unroll
    for (int mt = 0; mt < 4; mt++) {
        #pragma unroll
        for (int nt = 0; nt < 4; nt++) {
            const int col = col0 + nt * 16;
            const float bv = bias[col];
            #pragma unroll
            for (int r = 0; r < 4; r++) {
                const int row = row0 + mt * 16 + r;
                const float z = acc[mt][nt][r] + bv;
                if (MODE == 1) {
                    float carry = bf2f(A[(size_t)row * K + col]);
                    outB[(size_t)row * NOUT + col] = f2bf(carry + 0.1f * fast_tanh(z));
                } else if (MODE == 2) {
                    outB[(size_t)row * NOUT + col] = f2bf(fmaxf(z, 0.f));
                } else {
                    outF[(size_t)row * NOUT + col] = fast_tanh(z);
                }
            }
        }
    }
}

extern "C" void kernel_launch(void* const* d_in, const int* in_sizes, int n_in,
                              void* d_out, int out_size, void* d_ws, size_t ws_size,
                              hipStream_t stream) {
    const float* inp = (const float*)d_in[0];  // [32,1024,512]
    const float* hz  = (const float*)d_in[1];  // [32,1024,512]
    const float* Wf  = (const float*)d_in[2];  // [1024,1024]
    const float* bf_ = (const float*)d_in[3];  // [1024]
    const float* W1  = (const float*)d_in[4];  // [1024,1024]
    const float* b1  = (const float*)d_in[5];  // [1024]
    const float* W2  = (const float*)d_in[6];  // [1024,512]
    const float* b2  = (const float*)d_in[7];  // [512]
    float* out = (float*)d_out;                // [32,1024,512] fp32

    char* ws = (char*)d_ws;
    ushort* WfT  = (ushort*)(ws);                                  // 2 MB
    ushort* W1T  = (ushort*)(ws + (size_t)(2 << 20));              // 2 MB
    ushort* W2T  = (ushort*)(ws + (size_t)(4 << 20));              // 1 MB
    ushort* bufA = (ushort*)(ws + (size_t)(8 << 20));              // 64 MB
    ushort* bufB = (ushort*)(ws + (size_t)(8 << 20) + ((size_t)64 << 20));  // 64 MB

    // fused prep: h0 pack + 3 weight transposes, one dispatch
    prep<<<35328, 256, 0, stream>>>(inp, hz, Wf, W1, W2, bufA, WfT, W1T, W2T);

    // h1 = h0 + 0.1*tanh(h0@Wf + bf)
    gemm_ep<1, 1024, 4><<<1024, 512, 0, stream>>>(bufA, WfT, bf_, bufB, nullptr);
    // h2 = h1 + 0.1*tanh(h1@Wf + bf)
    gemm_ep<1, 1024, 4><<<1024, 512, 0, stream>>>(bufB, WfT, bf_, bufA, nullptr);
    // g = relu(h2@W1 + b1)
    gemm_ep<2, 1024, 4><<<1024, 512, 0, stream>>>(bufA, W1T, b1, bufB, nullptr);
    // out = tanh(g@W2 + b2)
    gemm_ep<3, 512, 2><<<512, 512, 0, stream>>>(bufB, W2T, b2, nullptr, out);
}

// Round 5
// 448.544 us; speedup vs baseline: 1.1314x; 1.1314x over previous
//
#include <hip/hip_runtime.h>
#include <hip/hip_bf16.h>

typedef __attribute__((ext_vector_type(8))) short short8;
typedef __attribute__((ext_vector_type(4))) float floatx4;

__device__ __forceinline__ ushort f2bf(float x) {
    __hip_bfloat16 h = __float2bfloat16(x);
    return __builtin_bit_cast(ushort, h);
}
__device__ __forceinline__ float bf2f(ushort u) {
    __hip_bfloat16 h = __builtin_bit_cast(__hip_bfloat16, u);
    return __bfloat162float(h);
}

// fast tanh: 1 - 2/(e^{2z}+1); v_exp + v_rcp, ~1e-6 abs err
__device__ __forceinline__ float fast_tanh(float z) {
    float e = __expf(2.0f * z);
    return 1.0f - 2.0f * __builtin_amdgcn_rcpf(e + 1.0f);
}

// async global -> LDS, 16 bytes per lane. LDS dest is wave-uniform base + lane*16;
// per-lane GLOBAL source is arbitrary (exploited for the XOR bank swizzle).
__device__ __forceinline__ void gload_lds16(const ushort* g, ushort* l) {
    __builtin_amdgcn_global_load_lds(
        (const __attribute__((address_space(1))) unsigned int*)(const void*)g,
        (__attribute__((address_space(3))) unsigned int*)(void*)l,
        16, 0, 0);
}

// ---------------------------------------------------------------------------
// Fused prep (one dispatch): h0 pack + all three weight transposes. (unchanged)
// ---------------------------------------------------------------------------
__global__ void prep(const float* __restrict__ inp, const float* __restrict__ hz,
                     const float* __restrict__ Wf, const float* __restrict__ W1,
                     const float* __restrict__ W2,
                     ushort* __restrict__ h0, ushort* __restrict__ WfT,
                     ushort* __restrict__ W1T, ushort* __restrict__ W2T) {
    int bid = blockIdx.x;
    int tid = threadIdx.x;
    __shared__ float tile[32][33];
    if (bid < 32768) {
        const float* src = (bid < 16384) ? inp : hz;
        int half = (bid < 16384) ? 0 : 1;
        int b = bid - half * 16384;
        size_t i = ((size_t)b * 256 + tid) * 4;   // over 32768*512 floats
        size_t row = i >> 9;
        int col = (int)(i & 511);
        float4 v = *(const float4*)(src + i);
        ushort4 o = make_ushort4(f2bf(v.x), f2bf(v.y), f2bf(v.z), f2bf(v.w));
        *(ushort4*)(h0 + row * 1024 + half * 512 + col) = o;
    } else {
        int t = bid - 32768;
        const float* W;
        ushort* WT;
        int K = 1024, N = 1024;
        if (t < 1024)      { W = Wf; WT = WfT; }
        else if (t < 2048) { W = W1; WT = W1T; t -= 1024; }
        else               { W = W2; WT = W2T; t -= 2048; N = 512; }
        int tx = tid & 31, ty = tid >> 5;
        int nb = (t % (N / 32)) * 32, kb = (t / (N / 32)) * 32;
        #pragma unroll
        for (int j = ty; j < 32; j += 8)
            tile[j][tx] = W[(size_t)(kb + j) * N + nb + tx];
        __syncthreads();
        #pragma unroll
        for (int j = ty; j < 32; j += 8)
            WT[(size_t)(nb + j) * K + kb + tx] = f2bf(tile[tx][j]);
    }
}

// ---------------------------------------------------------------------------
// 256x256-tile bf16 MFMA GEMM (m201-geometry port), 512 threads / 8 waves
// (2M x 4N), per-wave output 128x64 (acc[8][4]).
// Ring-4 of 32-k panels, each panel = 2 phases:
//   phase a: ds_read af0-3 + bfr0-3 (8 x b128) | stage A-halves(t+3)
//            | barrier | lgkm(0) | 16 MFMA (mt 0-3) | barrier
//   phase b: ds_read af4-7 (4 x b128, bfr reused in regs) | stage B-halves(t+3)
//            | vmcnt(8) | barrier | lgkm(0) | 16 MFMA (mt 4-7) | barrier
// 4 gloads/thread/panel; vmcnt(8) = 2 panels (t+2,t+3) stay in flight across
// barriers. LDS = 4 slots x (A 16KB + B 16KB) = 128 KB, 1 block/CU.
// LDS:MFMA ratio 0.375 KB/MFMA (vs 0.5 before) -> ~80% LDS-BW ceiling.
// Slot-reuse invariant: STAGE(t+3) -> slot (t-1)&3; all waves' reads of that
// slot finished before their lgkm(0)+closing barrier of panel t-1.
// MODE 1: out_bf = bf2f(A[row][col]) + 0.1*tanh(acc + bias)   (euler step)
// MODE 2: out_bf = relu(acc + bias)
// MODE 3: out_f32 = tanh(acc + bias)
// Grid 1-D: xcd=id&7 owns 16 M-tiles; N-tiles innermost for L2 A-reuse.
// ---------------------------------------------------------------------------
template <int MODE, int NOUT, int NX>
__global__ __launch_bounds__(512, 2) void gemm_ep(
    const ushort* __restrict__ A, const ushort* __restrict__ BT,
    const float* __restrict__ bias,
    ushort* __restrict__ outB, float* __restrict__ outF) {
    constexpr int K = 1024;
    __shared__ ushort As[4][8192];   // 4 slots x 256 rows x 32 k = 64 KB
    __shared__ ushort Bs[4][8192];   // 64 KB

    const int tid = threadIdx.x;
    const int wave = tid >> 6, lane = tid & 63;

    const int id = blockIdx.x;
    const int inner = id >> 3;
    const int nTile = inner % NX;
    const int mTile = (id & 7) * 16 + inner / NX;   // 128 M-tiles / 8 XCDs
    const int mBase = mTile * 256;
    const int nBase = nTile * 256;
    const int waveM = wave >> 2;      // 0..1  (128-row band)
    const int waveN = wave & 3;       // 0..3  (64-col band)

    // Staging: physical 16B slot c holds logical (row r=c>>2, quad
    // q=(c&3)^((r>>1)&3)) within a 128-row half; halves at +4096 ushorts.
    const int c = wave * 64 + lane;           // 0..511
    const int ra = c >> 2;                    // 0..127
    const int qa = (c & 3) ^ ((ra >> 1) & 3);
    const ushort* agA0 = A  + (size_t)(mBase + ra) * K + qa * 8;
    const ushort* agA1 = A  + (size_t)(mBase + 128 + ra) * K + qa * 8;
    const ushort* bgB0 = BT + (size_t)(nBase + ra) * K + qa * 8;
    const ushort* bgB1 = BT + (size_t)(nBase + 128 + ra) * K + qa * 8;
    ushort* asD = &As[0][0] + wave * 512;
    ushort* bsD = &Bs[0][0] + wave * 512;

    floatx4 acc[8][4];
    #pragma unroll
    for (int i = 0; i < 8; i++)
        #pragma unroll
        for (int j = 0; j < 4; j++) acc[i][j] = (floatx4)(0.f);

    const int mrow = lane & 15;
    const int g = lane >> 4;                  // logical k-quad
    const int pq = g ^ ((mrow >> 1) & 3);     // physical quad (uniform across
                                              // 16-row frags: offsets % 4 == 0)
    const ushort* aB = &As[0][0] + (waveM * 128 + mrow) * 32 + pq * 8;
    const ushort* bB = &Bs[0][0] + (waveN * 64 + mrow) * 32 + pq * 8;

#define MFMA_ROW(MT, AF)                                                            \
    acc[MT][0] = __builtin_amdgcn_mfma_f32_16x16x32_bf16(AF, bf0, acc[MT][0], 0,0,0); \
    acc[MT][1] = __builtin_amdgcn_mfma_f32_16x16x32_bf16(AF, bf1, acc[MT][1], 0,0,0); \
    acc[MT][2] = __builtin_amdgcn_mfma_f32_16x16x32_bf16(AF, bf2, acc[MT][2], 0,0,0); \
    acc[MT][3] = __builtin_amdgcn_mfma_f32_16x16x32_bf16(AF, bf3, acc[MT][3], 0,0,0);

#define PANEL(T, STG, VMASM)                                                   \
  {                                                                            \
    const int s  = (T) & 3;                                                    \
    const int s3 = ((T) + 3) & 3;                                              \
    /* ---- phase a: frags (rows 0..63 of band) + A staging ---- */            \
    short8 af0 = *(const short8*)(aB + s * 8192 + 0 * 512);                    \
    short8 af1 = *(const short8*)(aB + s * 8192 + 1 * 512);                    \
    short8 af2 = *(const short8*)(aB + s * 8192 + 2 * 512);                    \
    short8 af3 = *(const short8*)(aB + s * 8192 + 3 * 512);                    \
    short8 bf0 = *(const short8*)(bB + s * 8192 + 0 * 512);                    \
    short8 bf1 = *(const short8*)(bB + s * 8192 + 1 * 512);                    \
    short8 bf2 = *(const short8*)(bB + s * 8192 + 2 * 512);                    \
    short8 bf3 = *(const short8*)(bB + s * 8192 + 3 * 512);                    \
    if (STG) {                                                                 \
      gload_lds16(agA0 + ((T) + 3) * 32, asD + s3 * 8192);                     \
      gload_lds16(agA1 + ((T) + 3) * 32, asD + s3 * 8192 + 4096);              \
    }                                                                          \
    __builtin_amdgcn_s_barrier();                                              \
    asm volatile("s_waitcnt lgkmcnt(0)" ::: "memory");                         \
    __builtin_amdgcn_sched_barrier(0);                                         \
    __builtin_amdgcn_s_setprio(1);                                             \
    MFMA_ROW(0, af0) MFMA_ROW(1, af1) MFMA_ROW(2, af2) MFMA_ROW(3, af3)        \
    __builtin_amdgcn_s_setprio(0);                                             \
    __builtin_amdgcn_sched_barrier(0);                                         \
    __builtin_amdgcn_s_barrier();                                              \
    /* ---- phase b: frags (rows 64..127), bfr reused + B staging ---- */      \
    af0 = *(const short8*)(aB + s * 8192 + 2048 + 0 * 512);                    \
    af1 = *(const short8*)(aB + s * 8192 + 2048 + 1 * 512);                    \
    af2 = *(const short8*)(aB + s * 8192 + 2048 + 2 * 512);                    \
    af3 = *(const short8*)(aB + s * 8192 + 2048 + 3 * 512);                    \
    if (STG) {                                                                 \
      gload_lds16(bgB0 + ((T) + 3) * 32, bsD + s3 * 8192);                     \
      gload_lds16(bgB1 + ((T) + 3) * 32, bsD + s3 * 8192 + 4096);              \
    }                                                                          \
    asm volatile(VMASM ::: "memory");                                          \
    __builtin_amdgcn_s_barrier();                                              \
    asm volatile("s_waitcnt lgkmcnt(0)" ::: "memory");                         \
    __builtin_amdgcn_sched_barrier(0);                                         \
    __builtin_amdgcn_s_setprio(1);                                             \
    MFMA_ROW(4, af0) MFMA_ROW(5, af1) MFMA_ROW(6, af2) MFMA_ROW(7, af3)        \
    __builtin_amdgcn_s_setprio(0);                                             \
    __builtin_amdgcn_sched_barrier(0);                                         \
    __builtin_amdgcn_s_barrier();                                              \
  }

    // prologue: stage panels 0..2 (12 loads); vmcnt(8) -> panel 0 landed
    #pragma unroll
    for (int p = 0; p < 3; ++p) {
        gload_lds16(agA0 + p * 32, asD + p * 8192);
        gload_lds16(agA1 + p * 32, asD + p * 8192 + 4096);
        gload_lds16(bgB0 + p * 32, bsD + p * 8192);
        gload_lds16(bgB1 + p * 32, bsD + p * 8192 + 4096);
    }
    asm volatile("s_waitcnt vmcnt(8)" ::: "memory");
    __builtin_amdgcn_s_barrier();

    // main loop: 28 panels with steady-state vmcnt(8); explicit 4-body period
    // so (t&3) folds to compile-time slot constants.
    for (int tt = 0; tt < 7; ++tt) {
        const int t4 = tt * 4;
        PANEL(t4 + 0, true, "s_waitcnt vmcnt(8)")
        PANEL(t4 + 1, true, "s_waitcnt vmcnt(8)")
        PANEL(t4 + 2, true, "s_waitcnt vmcnt(8)")
        PANEL(t4 + 3, true, "s_waitcnt vmcnt(8)")
    }
    // graded tail: 28 stages panel 31; 29/30 drain panels 30/31; 31 clean
    PANEL(28, true,  "s_waitcnt vmcnt(8)")
    PANEL(29, false, "s_waitcnt vmcnt(4)")
    PANEL(30, false, "s_waitcnt vmcnt(0)")
    PANEL(31, false, "s_waitcnt vmcnt(0)")

#undef PANEL
#undef MFMA_ROW

    // epilogue: C/D layout col=lane&15, row=(lane>>4)*4+reg  [m89/m91]
    const int col0 = nBase + waveN * 64 + (lane & 15);
    const int row0 = mBase + waveM * 128 + (lane >> 4) * 4;
    #pragma unroll
    for (int mt = 0; mt < 8; mt++) {
        #pragma unroll
        for (int nt = 0; nt < 4; nt++) {
            const int col = col0 + nt * 16;
            const float bv = bias[col];
            #pragma unroll
            for (int r = 0; r < 4; r++) {
                const int row = row0 + mt * 16 + r;
                const float z = acc[mt][nt][r] + bv;
                if (MODE == 1) {
                    float carry = bf2f(A[(size_t)row * K + col]);
                    outB[(size_t)row * NOUT + col] = f2bf(carry + 0.1f * fast_tanh(z));
                } else if (MODE == 2) {
                    outB[(size_t)row * NOUT + col] = f2bf(fmaxf(z, 0.f));
                } else {
                    outF[(size_t)row * NOUT + col] = fast_tanh(z);
                }
            }
        }
    }
}

extern "C" void kernel_launch(void* const* d_in, const int* in_sizes, int n_in,
                              void* d_out, int out_size, void* d_ws, size_t ws_size,
                              hipStream_t stream) {
    const float* inp = (const float*)d_in[0];  // [32,1024,512]
    const float* hz  = (const float*)d_in[1];  // [32,1024,512]
    const float* Wf  = (const float*)d_in[2];  // [1024,1024]
    const float* bf_ = (const float*)d_in[3];  // [1024]
    const float* W1  = (const float*)d_in[4];  // [1024,1024]
    const float* b1  = (const float*)d_in[5];  // [1024]
    const float* W2  = (const float*)d_in[6];  // [1024,512]
    const float* b2  = (const float*)d_in[7];  // [512]
    float* out = (float*)d_out;                // [32,1024,512] fp32

    char* ws = (char*)d_ws;
    ushort* WfT  = (ushort*)(ws);                                  // 2 MB
    ushort* W1T  = (ushort*)(ws + (size_t)(2 << 20));              // 2 MB
    ushort* W2T  = (ushort*)(ws + (size_t)(4 << 20));              // 1 MB
    ushort* bufA = (ushort*)(ws + (size_t)(8 << 20));              // 64 MB
    ushort* bufB = (ushort*)(ws + (size_t)(8 << 20) + ((size_t)64 << 20));  // 64 MB

    // fused prep: h0 pack + 3 weight transposes, one dispatch
    prep<<<35328, 256, 0, stream>>>(inp, hz, Wf, W1, W2, bufA, WfT, W1T, W2T);

    // h1 = h0 + 0.1*tanh(h0@Wf + bf)      (128 M-tiles x 4 N-tiles)
    gemm_ep<1, 1024, 4><<<512, 512, 0, stream>>>(bufA, WfT, bf_, bufB, nullptr);
    // h2 = h1 + 0.1*tanh(h1@Wf + bf)
    gemm_ep<1, 1024, 4><<<512, 512, 0, stream>>>(bufB, WfT, bf_, bufA, nullptr);
    // g = relu(h2@W1 + b1)
    gemm_ep<2, 1024, 4><<<512, 512, 0, stream>>>(bufA, W1T, b1, bufB, nullptr);
    // out = tanh(g@W2 + b2)               (128 M-tiles x 2 N-tiles)
    gemm_ep<3, 512, 2><<<256, 512, 0, stream>>>(bufB, W2T, b2, nullptr, out);
}

// Round 7
// 425.670 us; speedup vs baseline: 1.1922x; 1.0537x over previous
//
#include <hip/hip_runtime.h>
#include <hip/hip_bf16.h>

typedef __attribute__((ext_vector_type(8))) short short8;
typedef __attribute__((ext_vector_type(4))) float floatx4;

__device__ __forceinline__ ushort f2bf(float x) {
    __hip_bfloat16 h = __float2bfloat16(x);
    return __builtin_bit_cast(ushort, h);
}
__device__ __forceinline__ float bf2f(ushort u) {
    __hip_bfloat16 h = __builtin_bit_cast(__hip_bfloat16, u);
    return __bfloat162float(h);
}

// fast tanh: 1 - 2/(e^{2z}+1); v_exp + v_rcp, ~1e-6 abs err
__device__ __forceinline__ float fast_tanh(float z) {
    float e = __expf(2.0f * z);
    return 1.0f - 2.0f * __builtin_amdgcn_rcpf(e + 1.0f);
}

// async global -> LDS, 16 bytes per lane. LDS dest is wave-uniform base + lane*16;
// per-lane GLOBAL source is arbitrary (exploited for the XOR bank swizzle).
__device__ __forceinline__ void gload_lds16(const ushort* g, ushort* l) {
    __builtin_amdgcn_global_load_lds(
        (const __attribute__((address_space(1))) unsigned int*)(const void*)g,
        (__attribute__((address_space(3))) unsigned int*)(void*)l,
        16, 0, 0);
}

// ---------------------------------------------------------------------------
// Fused prep (one dispatch): h0 pack + all three weight transposes. (unchanged)
// ---------------------------------------------------------------------------
__global__ void prep(const float* __restrict__ inp, const float* __restrict__ hz,
                     const float* __restrict__ Wf, const float* __restrict__ W1,
                     const float* __restrict__ W2,
                     ushort* __restrict__ h0, ushort* __restrict__ WfT,
                     ushort* __restrict__ W1T, ushort* __restrict__ W2T) {
    int bid = blockIdx.x;
    int tid = threadIdx.x;
    __shared__ float tile[32][33];
    if (bid < 32768) {
        const float* src = (bid < 16384) ? inp : hz;
        int half = (bid < 16384) ? 0 : 1;
        int b = bid - half * 16384;
        size_t i = ((size_t)b * 256 + tid) * 4;   // over 32768*512 floats
        size_t row = i >> 9;
        int col = (int)(i & 511);
        float4 v = *(const float4*)(src + i);
        ushort4 o = make_ushort4(f2bf(v.x), f2bf(v.y), f2bf(v.z), f2bf(v.w));
        *(ushort4*)(h0 + row * 1024 + half * 512 + col) = o;
    } else {
        int t = bid - 32768;
        const float* W;
        ushort* WT;
        int K = 1024, N = 1024;
        if (t < 1024)      { W = Wf; WT = WfT; }
        else if (t < 2048) { W = W1; WT = W1T; t -= 1024; }
        else               { W = W2; WT = W2T; t -= 2048; N = 512; }
        int tx = tid & 31, ty = tid >> 5;
        int nb = (t % (N / 32)) * 32, kb = (t / (N / 32)) * 32;
        #pragma unroll
        for (int j = ty; j < 32; j += 8)
            tile[j][tx] = W[(size_t)(kb + j) * N + nb + tx];
        __syncthreads();
        #pragma unroll
        for (int j = ty; j < 32; j += 8)
            WT[(size_t)(nb + j) * K + kb + tx] = f2bf(tile[tx][j]);
    }
}

// ---------------------------------------------------------------------------
// 256x256-tile bf16 MFMA GEMM, 512 threads / 8 waves (2M x 4N), per-wave
// output 128x64 (acc[8][4]). Ring-4 of 32-k panels.
//
// SYNC STRUCTURE: 2 barriers per panel, both in phase b. Phase a is
// barrier-free (own-data lgkmcnt(0) only) — waves drift within the panel,
// so one wave's MFMA overlaps another's ds_reads/staging (the
// role-diversity setprio exploits). Hazard ledger:
//  - drift window CLOSE(t-1)..OPEN(t): reads all hit slot t&3, writes all
//    hit slot (t-1)&3 — disjoint. OPEN(t)..CLOSE(t): MFMA only.
//  - availability(panel t): every wave's vmcnt(8) in panel t-1 retires
//    panel t's loads; OPEN/CLOSE of t-1 broadcast before any read.
//  - slot t&3 re-write: STAGE(t+4) in panel t+1 phase a, reachable only
//    after CLOSE(t), which follows every wave's lgkm(0) on slot-t reads.
// Per-wave vmcnt ledger: 4 gloads/panel, 12 outstanding at the vmcnt(8)
// point -> retires exactly panel t+1. Tail grades 8 -> 4 -> 0 -> 0.
//
// MODE 1: out_bf = bf2f(A[row][col]) + 0.1*tanh(acc + bias)   (euler step)
// MODE 2: out_bf = relu(acc + bias)
// MODE 3: out_f32 = tanh(acc + bias)
// Grid 1-D: xcd=id&7 owns 16 M-tiles; N-tiles innermost for L2 A-reuse.
// ---------------------------------------------------------------------------
template <int MODE, int NOUT, int NX>
__global__ __launch_bounds__(512, 2) void gemm_ep(
    const ushort* __restrict__ A, const ushort* __restrict__ BT,
    const float* __restrict__ bias,
    ushort* __restrict__ outB, float* __restrict__ outF) {
    constexpr int K = 1024;
    __shared__ ushort As[4][8192];   // 4 slots x 256 rows x 32 k = 64 KB
    __shared__ ushort Bs[4][8192];   // 64 KB

    const int tid = threadIdx.x;
    const int wave = tid >> 6, lane = tid & 63;

    const int id = blockIdx.x;
    const int inner = id >> 3;
    const int nTile = inner % NX;
    const int mTile = (id & 7) * 16 + inner / NX;   // 128 M-tiles / 8 XCDs
    const int mBase = mTile * 256;
    const int nBase = nTile * 256;
    const int waveM = wave >> 2;      // 0..1  (128-row band)
    const int waveN = wave & 3;       // 0..3  (64-col band)

    // Staging: physical 16B slot c holds logical (row r=c>>2, quad
    // q=(c&3)^((r>>1)&3)) within a 128-row half; halves at +4096 ushorts.
    const int c = wave * 64 + lane;           // 0..511
    const int ra = c >> 2;                    // 0..127
    const int qa = (c & 3) ^ ((ra >> 1) & 3);
    const ushort* agA0 = A  + (size_t)(mBase + ra) * K + qa * 8;
    const ushort* agA1 = A  + (size_t)(mBase + 128 + ra) * K + qa * 8;
    const ushort* bgB0 = BT + (size_t)(nBase + ra) * K + qa * 8;
    const ushort* bgB1 = BT + (size_t)(nBase + 128 + ra) * K + qa * 8;
    ushort* asD = &As[0][0] + wave * 512;
    ushort* bsD = &Bs[0][0] + wave * 512;

    floatx4 acc[8][4];
    #pragma unroll
    for (int i = 0; i < 8; i++)
        #pragma unroll
        for (int j = 0; j < 4; j++) acc[i][j] = (floatx4)(0.f);

    const int mrow = lane & 15;
    const int g = lane >> 4;                  // logical k-quad
    const int pq = g ^ ((mrow >> 1) & 3);     // physical quad (uniform across
                                              // 16-row frags: offsets % 4 == 0)
    const ushort* aB = &As[0][0] + (waveM * 128 + mrow) * 32 + pq * 8;
    const ushort* bB = &Bs[0][0] + (waveN * 64 + mrow) * 32 + pq * 8;

#define MFMA_ROW(MT, AF)                                                            \
    acc[MT][0] = __builtin_amdgcn_mfma_f32_16x16x32_bf16(AF, bf0, acc[MT][0], 0,0,0); \
    acc[MT][1] = __builtin_amdgcn_mfma_f32_16x16x32_bf16(AF, bf1, acc[MT][1], 0,0,0); \
    acc[MT][2] = __builtin_amdgcn_mfma_f32_16x16x32_bf16(AF, bf2, acc[MT][2], 0,0,0); \
    acc[MT][3] = __builtin_amdgcn_mfma_f32_16x16x32_bf16(AF, bf3, acc[MT][3], 0,0,0);

#define PANEL(T, STG, VMASM)                                                   \
  {                                                                            \
    const int s  = (T) & 3;                                                    \
    const int s3 = ((T) + 3) & 3;                                              \
    /* ---- phase a (barrier-free): frags rows 0..63 + A staging ---- */       \
    short8 af0 = *(const short8*)(aB + s * 8192 + 0 * 512);                    \
    short8 af1 = *(const short8*)(aB + s * 8192 + 1 * 512);                    \
    short8 af2 = *(const short8*)(aB + s * 8192 + 2 * 512);                    \
    short8 af3 = *(const short8*)(aB + s * 8192 + 3 * 512);                    \
    short8 bf0 = *(const short8*)(bB + s * 8192 + 0 * 512);                    \
    short8 bf1 = *(const short8*)(bB + s * 8192 + 1 * 512);                    \
    short8 bf2 = *(const short8*)(bB + s * 8192 + 2 * 512);                    \
    short8 bf3 = *(const short8*)(bB + s * 8192 + 3 * 512);                    \
    if (STG) {                                                                 \
      gload_lds16(agA0 + ((T) + 3) * 32, asD + s3 * 8192);                     \
      gload_lds16(agA1 + ((T) + 3) * 32, asD + s3 * 8192 + 4096);              \
    }                                                                          \
    asm volatile("s_waitcnt lgkmcnt(0)" ::: "memory");                         \
    __builtin_amdgcn_sched_barrier(0);                                         \
    __builtin_amdgcn_s_setprio(1);                                             \
    MFMA_ROW(0, af0) MFMA_ROW(1, af1) MFMA_ROW(2, af2) MFMA_ROW(3, af3)        \
    __builtin_amdgcn_s_setprio(0);                                             \
    /* ---- phase b: frags rows 64..127 (bfr reused) + B staging ---- */       \
    af0 = *(const short8*)(aB + s * 8192 + 2048 + 0 * 512);                    \
    af1 = *(const short8*)(aB + s * 8192 + 2048 + 1 * 512);                    \
    af2 = *(const short8*)(aB + s * 8192 + 2048 + 2 * 512);                    \
    af3 = *(const short8*)(aB + s * 8192 + 2048 + 3 * 512);                    \
    if (STG) {                                                                 \
      gload_lds16(bgB0 + ((T) + 3) * 32, bsD + s3 * 8192);                     \
      gload_lds16(bgB1 + ((T) + 3) * 32, bsD + s3 * 8192 + 4096);              \
    }                                                                          \
    asm volatile(VMASM ::: "memory");                                          \
    __builtin_amdgcn_s_barrier();      /* OPEN: availability broadcast */      \
    asm volatile("s_waitcnt lgkmcnt(0)" ::: "memory");                         \
    __builtin_amdgcn_sched_barrier(0);                                         \
    __builtin_amdgcn_s_setprio(1);                                             \
    MFMA_ROW(4, af0) MFMA_ROW(5, af1) MFMA_ROW(6, af2) MFMA_ROW(7, af3)        \
    __builtin_amdgcn_s_setprio(0);                                             \
    __builtin_amdgcn_sched_barrier(0);                                         \
    __builtin_amdgcn_s_barrier();      /* CLOSE: slot-reuse protection */      \
  }

    // prologue: stage panels 0..2 (12 loads); vmcnt(8) -> panel 0 landed
    #pragma unroll
    for (int p = 0; p < 3; ++p) {
        gload_lds16(agA0 + p * 32, asD + p * 8192);
        gload_lds16(agA1 + p * 32, asD + p * 8192 + 4096);
        gload_lds16(bgB0 + p * 32, bsD + p * 8192);
        gload_lds16(bgB1 + p * 32, bsD + p * 8192 + 4096);
    }
    asm volatile("s_waitcnt vmcnt(8)" ::: "memory");
    __builtin_amdgcn_s_barrier();

    // main loop: 28 panels with steady-state vmcnt(8); explicit 4-body period
    // so (t&3) folds to compile-time slot constants.
    for (int tt = 0; tt < 7; ++tt) {
        const int t4 = tt * 4;
        PANEL(t4 + 0, true, "s_waitcnt vmcnt(8)")
        PANEL(t4 + 1, true, "s_waitcnt vmcnt(8)")
        PANEL(t4 + 2, true, "s_waitcnt vmcnt(8)")
        PANEL(t4 + 3, true, "s_waitcnt vmcnt(8)")
    }
    // graded tail: 28 stages panel 31; 29/30 drain panels 30/31; 31 clean
    PANEL(28, true,  "s_waitcnt vmcnt(8)")
    PANEL(29, false, "s_waitcnt vmcnt(4)")
    PANEL(30, false, "s_waitcnt vmcnt(0)")
    PANEL(31, false, "s_waitcnt vmcnt(0)")

#undef PANEL
#undef MFMA_ROW

    // epilogue: C/D layout col=lane&15, row=(lane>>4)*4+reg  [m89/m91]
    const int col0 = nBase + waveN * 64 + (lane & 15);
    const int row0 = mBase + waveM * 128 + (lane >> 4) * 4;
    #pragma unroll
    for (int mt = 0; mt < 8; mt++) {
        #pragma unroll
        for (int nt = 0; nt < 4; nt++) {
            const int col = col0 + nt * 16;
            const float bv = bias[col];
            #pragma unroll
            for (int r = 0; r < 4; r++) {
                const int row = row0 + mt * 16 + r;
                const float z = acc[mt][nt][r] + bv;
                if (MODE == 1) {
                    float carry = bf2f(A[(size_t)row * K + col]);
                    outB[(size_t)row * NOUT + col] = f2bf(carry + 0.1f * fast_tanh(z));
                } else if (MODE == 2) {
                    outB[(size_t)row * NOUT + col] = f2bf(fmaxf(z, 0.f));
                } else {
                    outF[(size_t)row * NOUT + col] = fast_tanh(z);
                }
            }
        }
    }
}

extern "C" void kernel_launch(void* const* d_in, const int* in_sizes, int n_in,
                              void* d_out, int out_size, void* d_ws, size_t ws_size,
                              hipStream_t stream) {
    const float* inp = (const float*)d_in[0];  // [32,1024,512]
    const float* hz  = (const float*)d_in[1];  // [32,1024,512]
    const float* Wf  = (const float*)d_in[2];  // [1024,1024]
    const float* bf_ = (const float*)d_in[3];  // [1024]
    const float* W1  = (const float*)d_in[4];  // [1024,1024]
    const float* b1  = (const float*)d_in[5];  // [1024]
    const float* W2  = (const float*)d_in[6];  // [1024,512]
    const float* b2  = (const float*)d_in[7];  // [512]
    float* out = (float*)d_out;                // [32,1024,512] fp32

    char* ws = (char*)d_ws;
    ushort* WfT  = (ushort*)(ws);                                  // 2 MB
    ushort* W1T  = (ushort*)(ws + (size_t)(2 << 20));              // 2 MB
    ushort* W2T  = (ushort*)(ws + (size_t)(4 << 20));              // 1 MB
    ushort* bufA = (ushort*)(ws + (size_t)(8 << 20));              // 64 MB
    ushort* bufB = (ushort*)(ws + (size_t)(8 << 20) + ((size_t)64 << 20));  // 64 MB

    // fused prep: h0 pack + 3 weight transposes, one dispatch
    prep<<<35328, 256, 0, stream>>>(inp, hz, Wf, W1, W2, bufA, WfT, W1T, W2T);

    // h1 = h0 + 0.1*tanh(h0@Wf + bf)      (128 M-tiles x 4 N-tiles)
    gemm_ep<1, 1024, 4><<<512, 512, 0, stream>>>(bufA, WfT, bf_, bufB, nullptr);
    // h2 = h1 + 0.1*tanh(h1@Wf + bf)
    gemm_ep<1, 1024, 4><<<512, 512, 0, stream>>>(bufB, WfT, bf_, bufA, nullptr);
    // g = relu(h2@W1 + b1)
    gemm_ep<2, 1024, 4><<<512, 512, 0, stream>>>(bufA, W1T, b1, bufB, nullptr);
    // out = tanh(g@W2 + b2)               (128 M-tiles x 2 N-tiles)
    gemm_ep<3, 512, 2><<<256, 512, 0, stream>>>(bufB, W2T, b2, nullptr, out);
}